// Round 1
// baseline (303.432 us; speedup 1.0000x reference)
//
#include <hip/hip_runtime.h>

typedef __attribute__((ext_vector_type(8))) short short8;
typedef __attribute__((ext_vector_type(8))) unsigned short us8;
typedef __attribute__((ext_vector_type(4))) unsigned short us4;
typedef __attribute__((ext_vector_type(4))) float f32x4;

__device__ __forceinline__ float bf2f(unsigned short h) {
  return __uint_as_float(((unsigned int)h) << 16);
}
__device__ __forceinline__ unsigned short f2bf(float f) {
  unsigned int u = __float_as_uint(f);
  u += 0x7FFF + ((u >> 16) & 1);
  return (unsigned short)(u >> 16);
}

// async global->LDS, 16B per lane. LDS dest is wave-uniform base + lane*16.
__device__ __forceinline__ void gload16(const void* g, void* l) {
  __builtin_amdgcn_global_load_lds(
      (const __attribute__((address_space(1))) unsigned int*)g,
      (__attribute__((address_space(3))) unsigned int*)l, 16, 0, 0);
}

#define BM 128
#define BN 128
#define BK 32

struct EpiParams {
  const float* bias;   // [out cols] or null
  const float* aux0;   // EPI2: query_xyz ; EPI3: query_feat (residual)
  const float* aux1;   // EPI2: key_xyz
  long  saux;          // xyz batch stride (elements)
  float scale;         // EPI2: 1/sqrt(D)
};

// C[r][c] = sum_k A[r][k] * B[c][k]   (B^T input form; A,B bf16 row-major, K contiguous)
// grid: (N/BN, M/BM, batches)
template<int EPI>
__global__ __launch_bounds__(256)
void gemm_bt(const unsigned short* __restrict__ A, const unsigned short* __restrict__ B,
             void* __restrict__ Cout, int Kd, int lda, int ldb, int ldc,
             long sA, long sB, long sC, EpiParams ep)
{
  __shared__ __attribute__((aligned(16))) char smem[16384];
  char* Al = smem;
  char* Bl = smem + 8192;

  const int t    = threadIdx.x;
  const int lane = t & 63;
  const int wid  = t >> 6;
  const int wr   = wid >> 1;   // wave row (0..1)
  const int wc   = wid & 1;    // wave col (0..1)
  const int tr   = lane & 15;  // row/col within 16x16 frag
  const int tg   = lane >> 4;  // k-group

  const int bz    = blockIdx.z;
  const int rbase = blockIdx.y * BM;
  const int cbase = blockIdx.x * BN;

  const unsigned short* Ab = A + (long)bz * sA;
  const unsigned short* Bb = B + (long)bz * sB;
  const char* Asrc = (const char*)(Ab + (long)rbase * lda);
  const char* Bsrc = (const char*)(Bb + (long)cbase * ldb);
  const long lda_b = (long)lda * 2;
  const long ldb_b = (long)ldb * 2;

  f32x4 acc[4][4] = {};

  for (int k0 = 0; k0 < Kd; k0 += BK) {
    // stage A-tile [128][32] and B-tile [128][32] (8 KB each)
#pragma unroll
    for (int it = 0; it < 2; ++it) {
      const int boff = (it * 4 + wid) * 1024 + lane * 16; // byte offset in tile
      const int r  = boff >> 6;   // 64 B per row
      const int cb = boff & 63;
      gload16(Asrc + (long)r * lda_b + (k0 * 2 + cb), Al + (it * 4 + wid) * 1024);
      gload16(Bsrc + (long)r * ldb_b + (k0 * 2 + cb), Bl + (it * 4 + wid) * 1024);
    }
    __syncthreads();

    short8 af[4], bf[4];
#pragma unroll
    for (int m = 0; m < 4; ++m)
      af[m] = *(const short8*)(Al + ((wr * 64 + m * 16 + tr) * 32 + tg * 8) * 2);
#pragma unroll
    for (int n = 0; n < 4; ++n)
      bf[n] = *(const short8*)(Bl + ((wc * 64 + n * 16 + tr) * 32 + tg * 8) * 2);
#pragma unroll
    for (int m = 0; m < 4; ++m)
#pragma unroll
      for (int n = 0; n < 4; ++n)
        acc[m][n] = __builtin_amdgcn_mfma_f32_16x16x32_bf16(af[m], bf[n], acc[m][n], 0, 0, 0);
    __syncthreads();
  }

  // ---------------- epilogues ----------------
  if (EPI == 0) {  // bf16 out (+optional bias). used for Q, K, PV
    unsigned short* C = (unsigned short*)Cout + (long)bz * sC;
#pragma unroll
    for (int n = 0; n < 4; ++n) {
      const int col = cbase + wc * 64 + n * 16 + tr;
      const float bv = ep.bias ? ep.bias[col] : 0.f;
#pragma unroll
      for (int m = 0; m < 4; ++m) {
#pragma unroll
        for (int i = 0; i < 4; ++i) {
          const int row = rbase + wr * 64 + m * 16 + tg * 4 + i;
          C[(long)row * ldc + col] = f2bf(acc[m][n][i] + bv);
        }
      }
    }
  } else if (EPI == 1) {  // V-projection writing V^T: Vt[b][e][m], packed 4 rows
    unsigned short* C = (unsigned short*)Cout;
#pragma unroll
    for (int n = 0; n < 4; ++n) {
      const int col = cbase + wc * 64 + n * 16 + tr;  // e
      const float bv = ep.bias ? ep.bias[col] : 0.f;
#pragma unroll
      for (int m = 0; m < 4; ++m) {
        const int row0 = rbase + wr * 64 + m * 16 + tg * 4;  // global row = b*2048+mloc
        const int b  = row0 >> 11;
        const int ml = row0 & 2047;
        us4 v;
#pragma unroll
        for (int i = 0; i < 4; ++i) v[i] = f2bf(acc[m][n][i] + bv);
        *(us4*)(C + ((long)b * 512 + col) * 2048 + ml) = v;
      }
    }
  } else if (EPI == 2) {  // scores: acc*scale + distance bias, bf16 out
    // stage xyz for this tile into LDS (loop ended with barrier, LDS free)
    float* qs = (float*)smem;          // 128*3 floats
    float* ks = (float*)smem + 384;    // 128*3 floats
    if (t < 128) {
      const float* q = ep.aux0 + (long)bz * ep.saux + (long)(rbase + t) * 3;
      qs[t * 3] = q[0]; qs[t * 3 + 1] = q[1]; qs[t * 3 + 2] = q[2];
    } else {
      const int tt = t - 128;
      const float* k = ep.aux1 + (long)bz * ep.saux + (long)(cbase + tt) * 3;
      ks[tt * 3] = k[0]; ks[tt * 3 + 1] = k[1]; ks[tt * 3 + 2] = k[2];
    }
    __syncthreads();
    unsigned short* C = (unsigned short*)Cout + (long)bz * sC;
#pragma unroll
    for (int m = 0; m < 4; ++m) {
#pragma unroll
      for (int i = 0; i < 4; ++i) {
        const int rl = wr * 64 + m * 16 + tg * 4 + i;
        const float qx = qs[rl * 3], qy = qs[rl * 3 + 1], qz = qs[rl * 3 + 2];
#pragma unroll
        for (int n = 0; n < 4; ++n) {
          const int cl = wc * 64 + n * 16 + tr;
          const float dx = qx - ks[cl * 3];
          const float dy = qy - ks[cl * 3 + 1];
          const float dz = qz - ks[cl * 3 + 2];
          const float d2 = dx * dx + dy * dy + dz * dz;
          const float d  = sqrtf(fmaxf(d2, 1e-12f));
          // log(exp(-2d)+1e-8) ~= max(-2d, ln(1e-8)); error only where weight ~ e^-17
          const float bias = fmaxf(-2.f * d, -18.420680743952367f);
          C[(long)(rbase + rl) * ldc + (cbase + cl)] = f2bf(acc[m][n][i] * ep.scale + bias);
        }
      }
    }
  } else {  // EPI 3: fp32 out = acc + bias + residual(query_feat)
    float* C = (float*)Cout;
    const float* qf = ep.aux0;
#pragma unroll
    for (int n = 0; n < 4; ++n) {
      const int col = cbase + wc * 64 + n * 16 + tr;
      const float bv = ep.bias ? ep.bias[col] : 0.f;
#pragma unroll
      for (int m = 0; m < 4; ++m) {
#pragma unroll
        for (int i = 0; i < 4; ++i) {
          const int row = rbase + wr * 64 + m * 16 + tg * 4 + i;
          C[(long)row * 512 + col] = acc[m][n][i] + bv + qf[(long)row * 512 + col];
        }
      }
    }
  }
}

// in-place row softmax on bf16 S rows of length 2048; one wave per row
__global__ __launch_bounds__(256)
void softmax_rows(unsigned short* __restrict__ S)
{
  const int row  = blockIdx.x * 4 + (threadIdx.x >> 6);
  const int lane = threadIdx.x & 63;
  unsigned short* rp = S + (long)row * 2048;

  us8 v[4];
#pragma unroll
  for (int c = 0; c < 4; ++c) v[c] = *(const us8*)(rp + c * 512 + lane * 8);
  float f[32];
#pragma unroll
  for (int c = 0; c < 4; ++c)
#pragma unroll
    for (int j = 0; j < 8; ++j) f[c * 8 + j] = bf2f(v[c][j]);

  float mx = f[0];
#pragma unroll
  for (int i = 1; i < 32; ++i) mx = fmaxf(mx, f[i]);
#pragma unroll
  for (int off = 32; off; off >>= 1) mx = fmaxf(mx, __shfl_xor(mx, off, 64));

  float sum = 0.f;
#pragma unroll
  for (int i = 0; i < 32; ++i) { f[i] = __expf(f[i] - mx); sum += f[i]; }
#pragma unroll
  for (int off = 32; off; off >>= 1) sum += __shfl_xor(sum, off, 64);
  const float inv = 1.f / sum;

#pragma unroll
  for (int c = 0; c < 4; ++c) {
    us8 o;
#pragma unroll
    for (int j = 0; j < 8; ++j) o[j] = f2bf(f[c * 8 + j] * inv);
    *(us8*)(rp + c * 512 + lane * 8) = o;
  }
}

// LayerNorm rows of 512 fp32; one wave per row
__global__ __launch_bounds__(256)
void ln_rows(const float* __restrict__ X, const float* __restrict__ g,
             const float* __restrict__ b, float* __restrict__ O)
{
  const int row  = blockIdx.x * 4 + (threadIdx.x >> 6);
  const int lane = threadIdx.x & 63;
  const float* xp = X + (long)row * 512;

  f32x4 v0 = *(const f32x4*)(xp + lane * 4);
  f32x4 v1 = *(const f32x4*)(xp + 256 + lane * 4);

  float s = 0.f;
#pragma unroll
  for (int j = 0; j < 4; ++j) s += v0[j] + v1[j];
#pragma unroll
  for (int off = 32; off; off >>= 1) s += __shfl_xor(s, off, 64);
  const float mu = s * (1.f / 512.f);

  float vs = 0.f;
#pragma unroll
  for (int j = 0; j < 4; ++j) {
    float d0 = v0[j] - mu, d1 = v1[j] - mu;
    vs += d0 * d0 + d1 * d1;
  }
#pragma unroll
  for (int off = 32; off; off >>= 1) vs += __shfl_xor(vs, off, 64);
  const float r = rsqrtf(vs * (1.f / 512.f) + 1e-5f);

  f32x4 g0 = *(const f32x4*)(g + lane * 4);
  f32x4 g1 = *(const f32x4*)(g + 256 + lane * 4);
  f32x4 b0 = *(const f32x4*)(b + lane * 4);
  f32x4 b1 = *(const f32x4*)(b + 256 + lane * 4);

  f32x4 o0, o1;
#pragma unroll
  for (int j = 0; j < 4; ++j) {
    o0[j] = (v0[j] - mu) * r * g0[j] + b0[j];
    o1[j] = (v1[j] - mu) * r * g1[j] + b1[j];
  }
  float* op = O + (long)row * 512;
  *(f32x4*)(op + lane * 4) = o0;
  *(f32x4*)(op + 256 + lane * 4) = o1;
}

// fp32 -> bf16, 8 elements per thread
__global__ __launch_bounds__(256)
void cvt_bf16(const float* __restrict__ src, unsigned short* __restrict__ dst, int nvec)
{
  const int i = blockIdx.x * blockDim.x + threadIdx.x;
  if (i >= nvec) return;
  const f32x4* s = (const f32x4*)src;
  f32x4 a = s[(long)i * 2];
  f32x4 c = s[(long)i * 2 + 1];
  us8 o;
#pragma unroll
  for (int j = 0; j < 4; ++j) { o[j] = f2bf(a[j]); o[4 + j] = f2bf(c[j]); }
  *(us8*)(dst + (long)i * 8) = o;
}

extern "C" void kernel_launch(void* const* d_in, const int* in_sizes, int n_in,
                              void* d_out, int out_size, void* d_ws, size_t ws_size,
                              hipStream_t stream)
{
  const float* qxyz  = (const float*)d_in[0];
  const float* qfeat = (const float*)d_in[1];
  const float* kxyz  = (const float*)d_in[2];
  const float* kfeat = (const float*)d_in[3];
  const float* Wq = (const float*)d_in[4];
  const float* bq = (const float*)d_in[5];
  const float* Wk = (const float*)d_in[6];
  const float* bk = (const float*)d_in[7];
  const float* Wv = (const float*)d_in[8];
  const float* bv = (const float*)d_in[9];
  const float* Wo = (const float*)d_in[10];
  const float* bo = (const float*)d_in[11];
  const float* lng = (const float*)d_in[12];
  const float* lnb = (const float*)d_in[13];

  // workspace layout (bytes)
  const long SZ_FEAT = 16777216;            // 8*2048*512*2
  char* ws = (char*)d_ws;
  if (ws_size < (size_t)153092096) return;  // need ~153 MB

  unsigned short* XQ  = (unsigned short*)(ws);
  unsigned short* XK  = (unsigned short*)(ws + SZ_FEAT);
  unsigned short* QB  = (unsigned short*)(ws + 2 * SZ_FEAT);
  unsigned short* KB  = (unsigned short*)(ws + 3 * SZ_FEAT);
  unsigned short* VT  = (unsigned short*)(ws + 4 * SZ_FEAT);
  unsigned short* WQB = (unsigned short*)(ws + 5 * SZ_FEAT);
  unsigned short* WKB = WQB + 262144;
  unsigned short* WVB = WQB + 524288;
  unsigned short* WOB = WQB + 786432;
  unsigned short* SB  = (unsigned short*)(ws + 5 * SZ_FEAT + 2097152);
  unsigned short* ATT = QB;                 // alias: Q dead after scores GEMM
  float* XRES = (float*)ws;                 // alias: XQ/XK dead after projections

  // 1. conversions
  cvt_bf16<<<4096, 256, 0, stream>>>(qfeat, XQ, 1048576);
  cvt_bf16<<<4096, 256, 0, stream>>>(kfeat, XK, 1048576);
  cvt_bf16<<<128, 256, 0, stream>>>(Wq, WQB, 32768);
  cvt_bf16<<<128, 256, 0, stream>>>(Wk, WKB, 32768);
  cvt_bf16<<<128, 256, 0, stream>>>(Wv, WVB, 32768);
  cvt_bf16<<<128, 256, 0, stream>>>(Wo, WOB, 32768);

  // 2. projections
  EpiParams e0{}; e0.bias = bq;
  gemm_bt<0><<<dim3(4, 128, 1), 256, 0, stream>>>(XQ, WQB, QB, 512, 512, 512, 512, 0, 0, 0, e0);
  EpiParams e1{}; e1.bias = bk;
  gemm_bt<0><<<dim3(4, 128, 1), 256, 0, stream>>>(XK, WKB, KB, 512, 512, 512, 512, 0, 0, 0, e1);
  EpiParams e2{}; e2.bias = bv;
  gemm_bt<1><<<dim3(4, 128, 1), 256, 0, stream>>>(XK, WVB, VT, 512, 512, 512, 0, 0, 0, 0, e2);

  // 3. scores + distance bias
  EpiParams es{}; es.aux0 = qxyz; es.aux1 = kxyz; es.saux = 2048 * 3;
  es.scale = 0.044194173824159216f;  // 1/sqrt(512)
  gemm_bt<2><<<dim3(16, 16, 8), 256, 0, stream>>>(QB, KB, SB, 512, 512, 512, 2048,
                                                  (long)2048 * 512, (long)2048 * 512,
                                                  (long)2048 * 2048, es);

  // 4. softmax
  softmax_rows<<<4096, 256, 0, stream>>>(SB);

  // 5. attended = P @ V   (via Vt, gemm_bt)
  EpiParams ep{}; ep.bias = nullptr;
  gemm_bt<0><<<dim3(4, 16, 8), 256, 0, stream>>>(SB, VT, ATT, 2048, 2048, 2048, 512,
                                                 (long)2048 * 2048, (long)512 * 2048,
                                                 (long)2048 * 512, ep);

  // 6. out projection + bias + residual -> x (fp32)
  EpiParams eo{}; eo.bias = bo; eo.aux0 = qfeat;
  gemm_bt<3><<<dim3(4, 128, 1), 256, 0, stream>>>(ATT, WOB, XRES, 512, 512, 512, 512, 0, 0, 0, eo);

  // 7. LayerNorm -> out
  ln_rows<<<4096, 256, 0, stream>>>(XRES, lng, lnb, (float*)d_out);
}